// Round 15
// baseline (654.122 us; speedup 1.0000x reference)
//
#include <hip/hip_runtime.h>

typedef unsigned short u16;
typedef __attribute__((ext_vector_type(4)))  float  f32x4;
typedef __attribute__((ext_vector_type(16))) float  f32x16;
typedef __attribute__((ext_vector_type(4)))  float  float4v;
typedef __attribute__((ext_vector_type(4)))  unsigned short u16x4;
typedef __attribute__((ext_vector_type(8)))  unsigned short u16x8;
typedef __attribute__((ext_vector_type(8)))  short s16x8;
typedef __attribute__((ext_vector_type(4)))  unsigned int u32x4;

#define SEQ 4096
#define DA  2048
#define NH  16
#define DKV 128

__device__ __forceinline__ u16 f2bf(float f) {
    unsigned u = __builtin_bit_cast(unsigned, f);
    u += 0x7FFFu + ((u >> 16) & 1u);           // round-nearest-even
    return (u16)(u >> 16);
}
__device__ __forceinline__ float bf2f(u16 h) {
    return __builtin_bit_cast(float, (unsigned)h << 16);
}
__device__ __forceinline__ f32x4 mfma16(u16x8 a, u16x8 b, f32x4 c) {
    return __builtin_amdgcn_mfma_f32_16x16x32_bf16(
        __builtin_bit_cast(s16x8, a), __builtin_bit_cast(s16x8, b), c, 0, 0, 0);
}
__device__ __forceinline__ f32x16 mfma32(u16x8 a, u16x8 b, f32x16 c) {
    return __builtin_amdgcn_mfma_f32_32x32x16_bf16(
        __builtin_bit_cast(s16x8, a), __builtin_bit_cast(s16x8, b), c, 0, 0, 0);
}
__device__ __forceinline__ unsigned cvtpk(float lo, float hi) {
    unsigned r;
    asm("v_cvt_pk_bf16_f32 %0, %1, %2" : "=v"(r) : "v"(lo), "v"(hi));
    return r;
}
// direct-to-LDS 16B load: per-lane global src, wave-uniform LDS base (+lane*16)
__device__ __forceinline__ void gld16(const u16* g, u16* l) {
    __builtin_amdgcn_global_load_lds(
        (const __attribute__((address_space(1))) unsigned int*)g,
        (__attribute__((address_space(3))) unsigned int*)l, 16, 0, 0);
}
// swizzled LDS addressing, 128B rows: XOR row&7 into byte-bit-4..6
__device__ __forceinline__ char* ldsp(void* base, int row, int bcol, int rowbytes) {
    int off = row * rowbytes + bcol;
    off ^= (row & 7) << 4;
    return (char*)base + off;
}
// swizzled LDS addressing, 256B rows: XOR row&15 into byte-bit-4..7
__device__ __forceinline__ char* ldsp256(void* base, int row, int bcol) {
    int off = row * 256 + bcol;
    off ^= (row & 15) << 4;
    return (char*)base + off;
}

// ---------------------------------------------------------------------------
// Transpose + split-convert: in f32 [B][R][C] -> oh/ol bf16 [B][C][R]
// ---------------------------------------------------------------------------
__global__ void transpose_split_k(const float* __restrict__ in, u16* __restrict__ oh,
                                  u16* __restrict__ ol, int R, int C) {
    __shared__ float tile[32][33];
    int b  = blockIdx.z;
    int r0 = blockIdx.x * 32, c0 = blockIdx.y * 32;
    const float* src = in + (size_t)b * R * C;
    int t = threadIdx.x;
    {
        int cl = t & 31, r = t >> 5;
        for (int i = 0; i < 4; ++i)
            tile[r + 8 * i][cl] = src[(size_t)(r0 + r + 8 * i) * C + (c0 + cl)];
    }
    __syncthreads();
    int rl = t & 31, c = t >> 5;
    size_t obase = (size_t)b * R * C;
    for (int i = 0; i < 4; ++i) {
        int cw = c + 8 * i;
        float x = tile[rl][cw];
        u16 h = f2bf(x);
        size_t o = obase + (size_t)(c0 + cw) * R + (r0 + rl);
        oh[o] = h;
        if (ol) ol[o] = f2bf(x - bf2f(h));
    }
}

// ---------------------------------------------------------------------------
// Row-major split-convert: in f32 [n], scale -> oh (hi), ol (lo residual)
// ---------------------------------------------------------------------------
__global__ void split_cvt_k(const float* __restrict__ in, u16* __restrict__ oh,
                            u16* __restrict__ ol, float scale, int n) {
    int stride = gridDim.x * 256 * 4;
    for (int i = (blockIdx.x * 256 + threadIdx.x) * 4; i < n; i += stride) {
        float4v v = *(const float4v*)(in + i);
        u16x4 hv, lv;
#pragma unroll
        for (int j = 0; j < 4; ++j) {
            float x = v[j] * scale;
            u16 hh = f2bf(x);
            hv[j] = hh;
            lv[j] = f2bf(x - bf2f(hh));
        }
        *(u16x4*)(oh + i) = hv;
        if (ol) *(u16x4*)(ol + i) = lv;
    }
}

// ---------------------------------------------------------------------------
// Projection GEMM v2 (R12-exact structure): bf16 inputs, gld16 staging,
// single-buffered BK=64, 2 blocks/CU.
// MODE 0: V (1 chain) -> VT in BLOCKED PV-fragment layout (see attn PV).
// MODE 1: K split. MODE 2: Q split.
// ---------------------------------------------------------------------------
template <int MODE>
__global__ void __launch_bounds__(256, 2) proj2_k(const u16* __restrict__ ASh,
                                                  const u16* __restrict__ ASl,
                                                  const u16* __restrict__ BTh,
                                                  const u16* __restrict__ BTl,
                                                  u16* __restrict__ Oh,
                                                  u16* __restrict__ Ol) {
    __shared__ u16 sAh[128 * 64];
    __shared__ u16 sBh[128 * 64];
    __shared__ u16 sAl[MODE ? 128 * 64 : 8];
    __shared__ u16 sBl[MODE ? 128 * 64 : 8];

    int t = threadIdx.x;
    int h = blockIdx.y;
    int bm0 = blockIdx.x * 128;
    int lane = t & 63, w = t >> 6, wr = w >> 1, wc = w & 1;
    int g = lane >> 4, c = lane & 15;

    int rin = lane >> 3;
    int cg  = (lane & 7) ^ rin;

    f32x4 acc[4][4] = {};

    for (int k0 = 0; k0 < DA; k0 += 64) {
        __syncthreads();
#pragma unroll
        for (int j = 0; j < 4; ++j) {
            int chunk = w * 4 + j;
            int r = chunk * 8 + rin;
            size_t ga = (size_t)(bm0 + r) * DA + k0 + cg * 8;
            size_t gb = ((size_t)h * 128 + r) * DA + k0 + cg * 8;
            gld16(ASh + ga, &sAh[chunk * 512]);
            gld16(BTh + gb, &sBh[chunk * 512]);
            if (MODE) {
                gld16(ASl + ga, &sAl[chunk * 512]);
                gld16(BTl + gb, &sBl[chunk * 512]);
            }
        }
        __syncthreads();

        for (int kc = 0; kc < 2; ++kc) {
            int kb = (kc * 32 + g * 8) * 2;
            u16x8 ah[4], al[4], bh[4], bl[4];
            for (int m = 0; m < 4; ++m) {
                int row = wr * 64 + m * 16 + c;
                ah[m] = *(u16x8*)ldsp(sAh, row, kb, 128);
                if (MODE) al[m] = *(u16x8*)ldsp(sAl, row, kb, 128);
            }
            for (int n = 0; n < 4; ++n) {
                int row = wc * 64 + n * 16 + c;
                bh[n] = *(u16x8*)ldsp(sBh, row, kb, 128);
                if (MODE) bl[n] = *(u16x8*)ldsp(sBl, row, kb, 128);
            }
            for (int m = 0; m < 4; ++m)
                for (int n = 0; n < 4; ++n) {
                    acc[m][n] = mfma16(ah[m], bh[n], acc[m][n]);
                    if (MODE) {
                        acc[m][n] = mfma16(ah[m], bl[n], acc[m][n]);
                        acc[m][n] = mfma16(al[m], bh[n], acc[m][n]);
                    }
                }
        }
    }

    for (int m = 0; m < 4; ++m)
        for (int n = 0; n < 4; ++n) {
            int col  = wc * 64 + n * 16 + c;     // vdim for MODE 0
            int row0 = bm0 + wr * 64 + m * 16 + g * 4;
            if (MODE == 0) {
                // blocked PV-fragment layout:
                // idx = h*SEQ*DKV + (s>>6)*8192 + ((s>>4)&3)*2048
                //     + (vdim>>5)*512 + (((s>>3)&1)*32 + (vdim&31))*8 + (s&7)
                for (int j = 0; j < 4; ++j) {
                    int s = row0 + j;
                    size_t o = (size_t)h * (SEQ * DKV)
                             + (size_t)(s >> 6) * 8192
                             + (size_t)((s >> 4) & 3) * 2048
                             + (size_t)(col >> 5) * 512
                             + (size_t)(((s >> 3) & 1) * 32 + (col & 31)) * 8
                             + (s & 7);
                    Oh[o] = f2bf(acc[m][n][j]);
                }
            } else {
                for (int j = 0; j < 4; ++j) {
                    float v = acc[m][n][j];
                    u16 hh = f2bf(v);
                    size_t o = ((size_t)h * SEQ + row0 + j) * DKV + col;
                    Oh[o] = hh;
                    Ol[o] = f2bf(v - bf2f(hh));
                }
            }
        }
}

// ---------------------------------------------------------------------------
// Flash attention v4 = R12 structure, V moved from LDS to registers:
// VT is pre-blocked so each PV fragment chunk is base + lane*8 (coalesced
// global_load_dwordx4, L1/L2-resident). 16 fragments loaded at iter top,
// latency hidden under QK+softmax. LDS = K hi/lo dbuf only (64KB).
// 8 waves x 32 q = 256 q/block, single barrier/iter, T13 defer-rescale,
// XCD-aware grid decode.
// ---------------------------------------------------------------------------
__global__ void __launch_bounds__(512, 1) attn_k(const u16* __restrict__ QH,
                                                 const u16* __restrict__ QL,
                                                 const u16* __restrict__ KH,
                                                 const u16* __restrict__ KL,
                                                 const u16* __restrict__ VT,
                                                 u16* __restrict__ Abuf) {
    __shared__ u16 sKh[2][64 * 128];
    __shared__ u16 sKl[2][64 * 128];

    int t = threadIdx.x, lane = t & 63, w = t >> 6;   // w in 0..7
    int bid = blockIdx.x;
    int h  = (bid & 7) + 8 * ((bid >> 3) & 1);        // XCD x serves heads {x, x+8}
    int q0 = (bid >> 4) * 256;
    int c = lane & 31, hi = lane >> 5;
    int qrow = q0 + w * 32 + c;

    // Q fragments (B-operand layout): lane holds Q[qrow][dc*16 + hi*8 .. +7]
    u16x8 qh[8], ql[8];
    {
        size_t base = ((size_t)h * SEQ + qrow) * DKV + hi * 8;
#pragma unroll
        for (int dc = 0; dc < 8; ++dc) {
            qh[dc] = *(const u16x8*)(QH + base + dc * 16);
            ql[dc] = *(const u16x8*)(QL + base + dc * 16);
        }
    }

    f32x16 o[4] = {};
    float mrun = -3e38f, lrun = 0.f;

    const size_t kroot = (size_t)h * SEQ * DKV;
    const u16* vroot = VT + (size_t)h * DKV * SEQ;   // blocked layout

    auto stage = [&](int kv, int b) {
        const u16* khp = KH + kroot + (size_t)kv * DKV;
        const u16* klp = KL + kroot + (size_t)kv * DKV;
#pragma unroll
        for (int j = 0; j < 2; ++j) {
            int ci = w * 2 + j;                      // 1KB chunk index (0..15)
            int rK = ci * 4 + (lane >> 4);           // LDS row 0..63
            int cK = (lane & 15) ^ (rK & 15);        // inverse-swizzled granule col
            gld16(khp + rK * DKV + cK * 8, &sKh[b][ci * 512]);
            gld16(klp + rK * DKV + cK * 8, &sKl[b][ci * 512]);
        }
    };

    stage(0, 0);
    const int NT = SEQ / 64;
    for (int it = 0; it < NT; ++it) {
        int b = it & 1;
        __syncthreads();               // drains own stage(it) loads, syncs all waves

        // V fragments for THIS tile (coalesced, issued before next K stage so
        // in-order vmcnt retires them without forcing the K prefetch)
        const u16* vtile = vroot + (size_t)it * 8192;   // 64 kv x 128 vdim
        u16x8 va[8], vb[8];
#pragma unroll
        for (int i = 0; i < 8; ++i) {
            int kc = i >> 2, vt = i & 3;
            va[i] = *(const u16x8*)(vtile + (0 + kc) * 2048 + vt * 512 + lane * 8);
            vb[i] = *(const u16x8*)(vtile + (2 + kc) * 2048 + vt * 512 + lane * 8);
        }

        if (it + 1 < NT) stage((it + 1) * 64, b ^ 1);   // in flight under compute

        // S^T = K * Q^T : s[kt] holds S[kv=(r&3)+8*(r>>2)+4*hi + 32*kt][q=c]
        f32x16 s[2] = {};
        __builtin_amdgcn_s_setprio(1);
#pragma unroll
        for (int kt = 0; kt < 2; ++kt) {
#pragma unroll
            for (int dc = 0; dc < 8; ++dc) {
                u16x8 kh = *(u16x8*)ldsp256(sKh[b], kt * 32 + c, dc * 32 + hi * 16);
                u16x8 kl = *(u16x8*)ldsp256(sKl[b], kt * 32 + c, dc * 32 + hi * 16);
                s[kt] = mfma32(kh, qh[dc], s[kt]);
                s[kt] = mfma32(kl, qh[dc], s[kt]);
                s[kt] = mfma32(kh, ql[dc], s[kt]);
            }
        }
        __builtin_amdgcn_s_setprio(0);

        // online softmax with T13 defer-rescale (THR=8)
        float vmax = s[0][0];
#pragma unroll
        for (int r = 1; r < 16; ++r) vmax = fmaxf(vmax, s[0][r]);
#pragma unroll
        for (int r = 0; r < 16; ++r) vmax = fmaxf(vmax, s[1][r]);
        vmax = fmaxf(vmax, __shfl_xor(vmax, 32));
        if (!__all(vmax <= mrun + 8.0f)) {
            float mnew = fmaxf(mrun, vmax);
            float corr = __expf(mrun - mnew);
            mrun = mnew;
            lrun *= corr;
#pragma unroll
            for (int vt = 0; vt < 4; ++vt)
#pragma unroll
                for (int r = 0; r < 16; ++r) o[vt][r] *= corr;
        }
        float rs = 0.f;
#pragma unroll
        for (int kt = 0; kt < 2; ++kt)
#pragma unroll
            for (int r = 0; r < 16; ++r) {
                float p = __expf(s[kt][r] - mrun);
                s[kt][r] = p;
                rs += p;
            }
        rs += __shfl_xor(rs, 32);
        lrun += rs;

        // P -> B-frag (in-register) and PV: O^T += V^T · P^T (V from registers)
#pragma unroll
        for (int kt = 0; kt < 2; ++kt) {
            unsigned wv[8], xw[8];
#pragma unroll
            for (int i = 0; i < 8; ++i) wv[i] = cvtpk(s[kt][2 * i], s[kt][2 * i + 1]);
#pragma unroll
            for (int i = 0; i < 8; ++i) xw[i] = (unsigned)__shfl_xor((int)wv[i], 32);
            __builtin_amdgcn_s_setprio(1);
#pragma unroll
            for (int kc = 0; kc < 2; ++kc) {
                u32x4 pw;
                pw[0] = hi ? xw[4 * kc + 2] : wv[4 * kc + 0];
                pw[1] = hi ? xw[4 * kc + 3] : wv[4 * kc + 1];
                pw[2] = hi ? wv[4 * kc + 2] : xw[4 * kc + 0];
                pw[3] = hi ? wv[4 * kc + 3] : xw[4 * kc + 1];
                u16x8 pf = __builtin_bit_cast(u16x8, pw);
#pragma unroll
                for (int vt = 0; vt < 4; ++vt)
                    o[vt] = mfma32(kt == 0 ? va[kc * 4 + vt] : vb[kc * 4 + vt],
                                   pf, o[vt]);
            }
            __builtin_amdgcn_s_setprio(0);
        }
    }

    float inv = 1.0f / lrun;
#pragma unroll
    for (int vt = 0; vt < 4; ++vt)
#pragma unroll
        for (int rg = 0; rg < 4; ++rg) {
            u16x4 pv;
#pragma unroll
            for (int j = 0; j < 4; ++j) pv[j] = f2bf(o[vt][rg * 4 + j] * inv);
            *(u16x4*)(Abuf + (size_t)qrow * (NH * DKV) + h * DKV + vt * 32 + rg * 8 + hi * 4) = pv;
        }
}

// ---------------------------------------------------------------------------
// Final GEMM v2 (R12-exact): gld16 staging, single-buffered BK=64.
// ---------------------------------------------------------------------------
__global__ void __launch_bounds__(256, 2) gemm_out_k(const u16* __restrict__ Abuf,
                                                     const u16* __restrict__ WT,
                                                     float* __restrict__ out) {
    __shared__ u16 sA[128 * 64];
    __shared__ u16 sB[128 * 64];
    int t = threadIdx.x, lane = t & 63, w = t >> 6, wr = w >> 1, wc = w & 1;
    int g = lane >> 4, c = lane & 15;
    int bm0 = blockIdx.x * 128, bn0 = blockIdx.y * 128;
    int rin = lane >> 3;
    int cg  = (lane & 7) ^ rin;
    f32x4 acc[4][4] = {};

    for (int k0 = 0; k0 < DA; k0 += 64) {
        __syncthreads();
#pragma unroll
        for (int j = 0; j < 4; ++j) {
            int chunk = w * 4 + j;
            int r = chunk * 8 + rin;
            gld16(Abuf + (size_t)(bm0 + r) * DA + k0 + cg * 8, &sA[chunk * 512]);
            gld16(WT   + (size_t)(bn0 + r) * DA + k0 + cg * 8, &sB[chunk * 512]);
        }
        __syncthreads();

        for (int kc = 0; kc < 2; ++kc) {
            int kb = (kc * 32 + g * 8) * 2;
            u16x8 af[4], bfq[4];
            for (int m = 0; m < 4; ++m) af[m]  = *(u16x8*)ldsp(sA, wr * 64 + m * 16 + c, kb, 128);
            for (int n = 0; n < 4; ++n) bfq[n] = *(u16x8*)ldsp(sB, wc * 64 + n * 16 + c, kb, 128);
            for (int m = 0; m < 4; ++m)
                for (int n = 0; n < 4; ++n)
                    acc[m][n] = mfma16(af[m], bfq[n], acc[m][n]);
        }
    }
    for (int m = 0; m < 4; ++m)
        for (int n = 0; n < 4; ++n) {
            int row0 = bm0 + wr * 64 + m * 16 + g * 4;
            int col  = bn0 + wc * 64 + n * 16 + c;
            for (int j = 0; j < 4; ++j)
                out[(size_t)(row0 + j) * DA + col] = acc[m][n][j];
        }
}

// ---------------------------------------------------------------------------
extern "C" void kernel_launch(void* const* d_in, const int* in_sizes, int n_in,
                              void* d_out, int out_size, void* d_ws, size_t ws_size,
                              hipStream_t stream) {
    const float* queries = (const float*)d_in[0];
    const float* keys    = (const float*)d_in[1];
    const float* values  = (const float*)d_in[2];
    const float* Eq      = (const float*)d_in[3];
    const float* Ek      = (const float*)d_in[4];
    const float* Ev      = (const float*)d_in[5];
    const float* Wout    = (const float*)d_in[6];
    float* out = (float*)d_out;

    const size_t PROJ = (size_t)NH * SEQ * DKV;   // 8,388,608 elems
    const size_t TSZ  = (size_t)DA * DA;          // 4,194,304 elems
    const size_t ASZ  = (size_t)SEQ * DA;         // 8,388,608 elems
    u16* p  = (u16*)d_ws;
    u16* QH = p; p += PROJ;
    u16* QL = p; p += PROJ;
    u16* KH = p; p += PROJ;
    u16* KL = p; p += PROJ;
    u16* VT = p; p += PROJ;
    u16* AB = p; p += (size_t)SEQ * NH * DKV;
    u16* TH = p; p += TSZ;
    u16* TL = p; p += TSZ;
    u16* Sh = p; p += ASZ;
    u16* Sl = p; p += ASZ;

    dim3 tgE(DA / 32, DKV / 32, NH);   // E transposes
    dim3 tgW(DA / 32, DA / 32, 1);     // W transpose
    dim3 pg(SEQ / 128, NH);
    const int NELEM = SEQ * DA;

    // Q chain (queries pre-scaled by 1/128 — power of 2, exact)
    transpose_split_k<<<tgE, 256, 0, stream>>>(Eq, TH, TL, DA, DKV);
    split_cvt_k<<<2048, 256, 0, stream>>>(queries, Sh, Sl, 1.0f / 128.0f, NELEM);
    proj2_k<2><<<pg, 256, 0, stream>>>(Sh, Sl, TH, TL, QH, QL);
    // K chain
    transpose_split_k<<<tgE, 256, 0, stream>>>(Ek, TH, TL, DA, DKV);
    split_cvt_k<<<2048, 256, 0, stream>>>(keys, Sh, Sl, 1.0f, NELEM);
    proj2_k<1><<<pg, 256, 0, stream>>>(Sh, Sl, TH, TL, KH, KL);
    // V chain (hi only; blocked VT layout)
    transpose_split_k<<<tgE, 256, 0, stream>>>(Ev, TH, nullptr, DA, DKV);
    split_cvt_k<<<2048, 256, 0, stream>>>(values, Sh, nullptr, 1.0f, NELEM);
    proj2_k<0><<<pg, 256, 0, stream>>>(Sh, nullptr, TH, nullptr, VT, nullptr);
    // W transpose (hi only)
    transpose_split_k<<<tgW, 256, 0, stream>>>(Wout, TH, nullptr, DA, DA);
    // attention (256 blocks, 512 thr)
    attn_k<<<dim3(SEQ / 256 * NH), 512, 0, stream>>>(QH, QL, KH, KL, VT, AB);
    // output projection
    gemm_out_k<<<dim3(SEQ / 128, DA / 128), 256, 0, stream>>>(AB, TH, out);
}

// Round 16
// 576.823 us; speedup vs baseline: 1.1340x; 1.1340x over previous
//
#include <hip/hip_runtime.h>

typedef unsigned short u16;
typedef __attribute__((ext_vector_type(4)))  float  f32x4;
typedef __attribute__((ext_vector_type(16))) float  f32x16;
typedef __attribute__((ext_vector_type(4)))  float  float4v;
typedef __attribute__((ext_vector_type(4)))  unsigned short u16x4;
typedef __attribute__((ext_vector_type(8)))  unsigned short u16x8;
typedef __attribute__((ext_vector_type(8)))  short s16x8;
typedef __attribute__((ext_vector_type(4)))  unsigned int u32x4;

#define SEQ 4096
#define DA  2048
#define NH  16
#define DKV 128

__device__ __forceinline__ u16 f2bf(float f) {
    unsigned u = __builtin_bit_cast(unsigned, f);
    u += 0x7FFFu + ((u >> 16) & 1u);           // round-nearest-even
    return (u16)(u >> 16);
}
__device__ __forceinline__ float bf2f(u16 h) {
    return __builtin_bit_cast(float, (unsigned)h << 16);
}
__device__ __forceinline__ f32x4 mfma16(u16x8 a, u16x8 b, f32x4 c) {
    return __builtin_amdgcn_mfma_f32_16x16x32_bf16(
        __builtin_bit_cast(s16x8, a), __builtin_bit_cast(s16x8, b), c, 0, 0, 0);
}
__device__ __forceinline__ f32x16 mfma32(u16x8 a, u16x8 b, f32x16 c) {
    return __builtin_amdgcn_mfma_f32_32x32x16_bf16(
        __builtin_bit_cast(s16x8, a), __builtin_bit_cast(s16x8, b), c, 0, 0, 0);
}
__device__ __forceinline__ unsigned cvtpk(float lo, float hi) {
    unsigned r;
    asm("v_cvt_pk_bf16_f32 %0, %1, %2" : "=v"(r) : "v"(lo), "v"(hi));
    return r;
}
// direct-to-LDS 16B load: per-lane global src, wave-uniform LDS base (+lane*16)
__device__ __forceinline__ void gld16(const u16* g, u16* l) {
    __builtin_amdgcn_global_load_lds(
        (const __attribute__((address_space(1))) unsigned int*)g,
        (__attribute__((address_space(3))) unsigned int*)l, 16, 0, 0);
}
// swizzled LDS addressing, 128B rows: XOR row&7 into byte-bit-4..6
__device__ __forceinline__ char* ldsp(void* base, int row, int bcol, int rowbytes) {
    int off = row * rowbytes + bcol;
    off ^= (row & 7) << 4;
    return (char*)base + off;
}
// swizzled LDS addressing, 256B rows: XOR row&15 into byte-bit-4..7
__device__ __forceinline__ char* ldsp256(void* base, int row, int bcol) {
    int off = row * 256 + bcol;
    off ^= (row & 15) << 4;
    return (char*)base + off;
}

// ---------------------------------------------------------------------------
// Transpose + split-convert: in f32 [B][R][C] -> oh/ol bf16 [B][C][R]
// ---------------------------------------------------------------------------
__global__ void transpose_split_k(const float* __restrict__ in, u16* __restrict__ oh,
                                  u16* __restrict__ ol, int R, int C) {
    __shared__ float tile[32][33];
    int b  = blockIdx.z;
    int r0 = blockIdx.x * 32, c0 = blockIdx.y * 32;
    const float* src = in + (size_t)b * R * C;
    int t = threadIdx.x;
    {
        int cl = t & 31, r = t >> 5;
        for (int i = 0; i < 4; ++i)
            tile[r + 8 * i][cl] = src[(size_t)(r0 + r + 8 * i) * C + (c0 + cl)];
    }
    __syncthreads();
    int rl = t & 31, c = t >> 5;
    size_t obase = (size_t)b * R * C;
    for (int i = 0; i < 4; ++i) {
        int cw = c + 8 * i;
        float x = tile[rl][cw];
        u16 h = f2bf(x);
        size_t o = obase + (size_t)(c0 + cw) * R + (r0 + rl);
        oh[o] = h;
        if (ol) ol[o] = f2bf(x - bf2f(h));
    }
}

// ---------------------------------------------------------------------------
// Row-major split-convert: in f32 [n], scale -> oh (hi), ol (lo residual)
// ---------------------------------------------------------------------------
__global__ void split_cvt_k(const float* __restrict__ in, u16* __restrict__ oh,
                            u16* __restrict__ ol, float scale, int n) {
    int stride = gridDim.x * 256 * 4;
    for (int i = (blockIdx.x * 256 + threadIdx.x) * 4; i < n; i += stride) {
        float4v v = *(const float4v*)(in + i);
        u16x4 hv, lv;
#pragma unroll
        for (int j = 0; j < 4; ++j) {
            float x = v[j] * scale;
            u16 hh = f2bf(x);
            hv[j] = hh;
            lv[j] = f2bf(x - bf2f(hh));
        }
        *(u16x4*)(oh + i) = hv;
        if (ol) *(u16x4*)(ol + i) = lv;
    }
}

// ---------------------------------------------------------------------------
// Projection GEMM v2 (R12-exact): pure-bf16 inputs, gld16 staging,
// single-buffered BK=64, 2 blocks/CU.
// MODE 0: V (1 chain) -> VT[h][v][s]. MODE 1: K split. MODE 2: Q split.
// ---------------------------------------------------------------------------
template <int MODE>
__global__ void __launch_bounds__(256, 2) proj2_k(const u16* __restrict__ ASh,
                                                  const u16* __restrict__ ASl,
                                                  const u16* __restrict__ BTh,
                                                  const u16* __restrict__ BTl,
                                                  u16* __restrict__ Oh,
                                                  u16* __restrict__ Ol) {
    __shared__ u16 sAh[128 * 64];
    __shared__ u16 sBh[128 * 64];
    __shared__ u16 sAl[MODE ? 128 * 64 : 8];
    __shared__ u16 sBl[MODE ? 128 * 64 : 8];

    int t = threadIdx.x;
    int h = blockIdx.y;
    int bm0 = blockIdx.x * 128;
    int lane = t & 63, w = t >> 6, wr = w >> 1, wc = w & 1;
    int g = lane >> 4, c = lane & 15;

    int rin = lane >> 3;
    int cg  = (lane & 7) ^ rin;

    f32x4 acc[4][4] = {};

    for (int k0 = 0; k0 < DA; k0 += 64) {
        __syncthreads();
#pragma unroll
        for (int j = 0; j < 4; ++j) {
            int chunk = w * 4 + j;
            int r = chunk * 8 + rin;
            size_t ga = (size_t)(bm0 + r) * DA + k0 + cg * 8;
            size_t gb = ((size_t)h * 128 + r) * DA + k0 + cg * 8;
            gld16(ASh + ga, &sAh[chunk * 512]);
            gld16(BTh + gb, &sBh[chunk * 512]);
            if (MODE) {
                gld16(ASl + ga, &sAl[chunk * 512]);
                gld16(BTl + gb, &sBl[chunk * 512]);
            }
        }
        __syncthreads();

        for (int kc = 0; kc < 2; ++kc) {
            int kb = (kc * 32 + g * 8) * 2;
            u16x8 ah[4], al[4], bh[4], bl[4];
            for (int m = 0; m < 4; ++m) {
                int row = wr * 64 + m * 16 + c;
                ah[m] = *(u16x8*)ldsp(sAh, row, kb, 128);
                if (MODE) al[m] = *(u16x8*)ldsp(sAl, row, kb, 128);
            }
            for (int n = 0; n < 4; ++n) {
                int row = wc * 64 + n * 16 + c;
                bh[n] = *(u16x8*)ldsp(sBh, row, kb, 128);
                if (MODE) bl[n] = *(u16x8*)ldsp(sBl, row, kb, 128);
            }
            for (int m = 0; m < 4; ++m)
                for (int n = 0; n < 4; ++n) {
                    acc[m][n] = mfma16(ah[m], bh[n], acc[m][n]);
                    if (MODE) {
                        acc[m][n] = mfma16(ah[m], bl[n], acc[m][n]);
                        acc[m][n] = mfma16(al[m], bh[n], acc[m][n]);
                    }
                }
        }
    }

    for (int m = 0; m < 4; ++m)
        for (int n = 0; n < 4; ++n) {
            int col  = wc * 64 + n * 16 + c;
            int row0 = bm0 + wr * 64 + m * 16 + g * 4;
            if (MODE == 0) {
                u16x4 pv;
                for (int j = 0; j < 4; ++j) pv[j] = f2bf(acc[m][n][j]);
                *(u16x4*)(Oh + ((size_t)h * DKV + col) * SEQ + row0) = pv;
            } else {
                for (int j = 0; j < 4; ++j) {
                    float v = acc[m][n][j];
                    u16 hh = f2bf(v);
                    size_t o = ((size_t)h * SEQ + row0 + j) * DKV + col;
                    Oh[o] = hh;
                    Ol[o] = f2bf(v - bf2f(hh));
                }
            }
        }
}

// ---------------------------------------------------------------------------
// Flash attention — R12-exact kernel (measured 263 µs, absmax 64).
// ---------------------------------------------------------------------------
__global__ void __launch_bounds__(512, 1) attn_k(const u16* __restrict__ QH,
                                                 const u16* __restrict__ QL,
                                                 const u16* __restrict__ KH,
                                                 const u16* __restrict__ KL,
                                                 const u16* __restrict__ VT,
                                                 u16* __restrict__ Abuf) {
    __shared__ u16 sKh[2][64 * 128];
    __shared__ u16 sKl[2][64 * 128];
    __shared__ u16 sV [2][64 * 128];   // [64 rows][256B]: row r, half p = vdim p*64+r

    int t = threadIdx.x, lane = t & 63, w = t >> 6;   // w in 0..7
    int bid = blockIdx.x;
    int h  = (bid & 7) + 8 * ((bid >> 3) & 1);        // XCD x serves heads {x, x+8}
    int q0 = (bid >> 4) * 256;
    int c = lane & 31, hi = lane >> 5;
    int qrow = q0 + w * 32 + c;

    // Q fragments (B-operand layout): lane holds Q[qrow][dc*16 + hi*8 .. +7]
    u16x8 qh[8], ql[8];
    {
        size_t base = ((size_t)h * SEQ + qrow) * DKV + hi * 8;
#pragma unroll
        for (int dc = 0; dc < 8; ++dc) {
            qh[dc] = *(const u16x8*)(QH + base + dc * 16);
            ql[dc] = *(const u16x8*)(QL + base + dc * 16);
        }
    }

    f32x16 o[4] = {};
    float mrun = -3e38f, lrun = 0.f;

    const size_t kroot = (size_t)h * SEQ * DKV;
    const size_t vroot = (size_t)h * DKV * SEQ;

    auto stage = [&](int kv, int b) {
        const u16* khp = KH + kroot + (size_t)kv * DKV;
        const u16* klp = KL + kroot + (size_t)kv * DKV;
        const u16* vtp = VT + vroot + kv;
#pragma unroll
        for (int j = 0; j < 2; ++j) {
            int ci = w * 2 + j;                      // 1KB chunk index (0..15)
            int rK = ci * 4 + (lane >> 4);           // LDS row 0..63
            int cK = (lane & 15) ^ (rK & 15);        // inverse-swizzled granule col
            gld16(khp + rK * DKV + cK * 8, &sKh[b][ci * 512]);
            gld16(klp + rK * DKV + cK * 8, &sKl[b][ci * 512]);
            int vd = ((cK >> 3) << 6) + rK;          // vdim for V gather
            gld16(vtp + (size_t)vd * SEQ + (cK & 7) * 8, &sV[b][ci * 512]);
        }
    };

    stage(0, 0);
    const int NT = SEQ / 64;
    for (int it = 0; it < NT; ++it) {
        int b = it & 1;
        __syncthreads();               // drains own stage(it) loads, syncs all waves
        if (it + 1 < NT) stage((it + 1) * 64, b ^ 1);   // in flight under compute

        // S^T = K * Q^T : s[kt] holds S[kv=(r&3)+8*(r>>2)+4*hi + 32*kt][q=c]
        f32x16 s[2] = {};
        __builtin_amdgcn_s_setprio(1);
#pragma unroll
        for (int kt = 0; kt < 2; ++kt) {
#pragma unroll
            for (int dc = 0; dc < 8; ++dc) {
                u16x8 kh = *(u16x8*)ldsp256(sKh[b], kt * 32 + c, dc * 32 + hi * 16);
                u16x8 kl = *(u16x8*)ldsp256(sKl[b], kt * 32 + c, dc * 32 + hi * 16);
                s[kt] = mfma32(kh, qh[dc], s[kt]);
                s[kt] = mfma32(kl, qh[dc], s[kt]);
                s[kt] = mfma32(kh, ql[dc], s[kt]);
            }
        }
        __builtin_amdgcn_s_setprio(0);

        // online softmax with T13 defer-rescale (THR=8)
        float vmax = s[0][0];
#pragma unroll
        for (int r = 1; r < 16; ++r) vmax = fmaxf(vmax, s[0][r]);
#pragma unroll
        for (int r = 0; r < 16; ++r) vmax = fmaxf(vmax, s[1][r]);
        vmax = fmaxf(vmax, __shfl_xor(vmax, 32));
        if (!__all(vmax <= mrun + 8.0f)) {
            float mnew = fmaxf(mrun, vmax);
            float corr = __expf(mrun - mnew);
            mrun = mnew;
            lrun *= corr;
#pragma unroll
            for (int vt = 0; vt < 4; ++vt)
#pragma unroll
                for (int r = 0; r < 16; ++r) o[vt][r] *= corr;
        }
        float rs = 0.f;
#pragma unroll
        for (int kt = 0; kt < 2; ++kt)
#pragma unroll
            for (int r = 0; r < 16; ++r) {
                float p = __expf(s[kt][r] - mrun);
                s[kt][r] = p;
                rs += p;
            }
        rs += __shfl_xor(rs, 32);
        lrun += rs;

        // P -> B-frag (in-register) and PV: O^T += V^T · P^T
#pragma unroll
        for (int kt = 0; kt < 2; ++kt) {
            unsigned wv[8], xw[8];
#pragma unroll
            for (int i = 0; i < 8; ++i) wv[i] = cvtpk(s[kt][2 * i], s[kt][2 * i + 1]);
#pragma unroll
            for (int i = 0; i < 8; ++i) xw[i] = (unsigned)__shfl_xor((int)wv[i], 32);
            __builtin_amdgcn_s_setprio(1);
#pragma unroll
            for (int kc = 0; kc < 2; ++kc) {
                u32x4 pw;
                pw[0] = hi ? xw[4 * kc + 2] : wv[4 * kc + 0];
                pw[1] = hi ? xw[4 * kc + 3] : wv[4 * kc + 1];
                pw[2] = hi ? wv[4 * kc + 2] : xw[4 * kc + 0];
                pw[3] = hi ? wv[4 * kc + 3] : xw[4 * kc + 1];
                u16x8 pf = __builtin_bit_cast(u16x8, pw);
#pragma unroll
                for (int vt = 0; vt < 4; ++vt) {
                    int v = vt * 32 + c;
                    u16x8 vf = *(u16x8*)ldsp256(sV[b], v & 63,
                                                ((v >> 6) << 7) + kt * 64 + kc * 32 + hi * 16);
                    o[vt] = mfma32(vf, pf, o[vt]);
                }
            }
            __builtin_amdgcn_s_setprio(0);
        }
    }

    float inv = 1.0f / lrun;
#pragma unroll
    for (int vt = 0; vt < 4; ++vt)
#pragma unroll
        for (int rg = 0; rg < 4; ++rg) {
            u16x4 pv;
#pragma unroll
            for (int j = 0; j < 4; ++j) pv[j] = f2bf(o[vt][rg * 4 + j] * inv);
            *(u16x4*)(Abuf + (size_t)qrow * (NH * DKV) + h * DKV + vt * 32 + rg * 8 + hi * 4) = pv;
        }
}

// ---------------------------------------------------------------------------
// Final GEMM v2 (R12-exact): gld16 staging, single-buffered BK=64.
// ---------------------------------------------------------------------------
__global__ void __launch_bounds__(256, 2) gemm_out_k(const u16* __restrict__ Abuf,
                                                     const u16* __restrict__ WT,
                                                     float* __restrict__ out) {
    __shared__ u16 sA[128 * 64];
    __shared__ u16 sB[128 * 64];
    int t = threadIdx.x, lane = t & 63, w = t >> 6, wr = w >> 1, wc = w & 1;
    int g = lane >> 4, c = lane & 15;
    int bm0 = blockIdx.x * 128, bn0 = blockIdx.y * 128;
    int rin = lane >> 3;
    int cg  = (lane & 7) ^ rin;
    f32x4 acc[4][4] = {};

    for (int k0 = 0; k0 < DA; k0 += 64) {
        __syncthreads();
#pragma unroll
        for (int j = 0; j < 4; ++j) {
            int chunk = w * 4 + j;
            int r = chunk * 8 + rin;
            gld16(Abuf + (size_t)(bm0 + r) * DA + k0 + cg * 8, &sA[chunk * 512]);
            gld16(WT   + (size_t)(bn0 + r) * DA + k0 + cg * 8, &sB[chunk * 512]);
        }
        __syncthreads();

        for (int kc = 0; kc < 2; ++kc) {
            int kb = (kc * 32 + g * 8) * 2;
            u16x8 af[4], bfq[4];
            for (int m = 0; m < 4; ++m) af[m]  = *(u16x8*)ldsp(sA, wr * 64 + m * 16 + c, kb, 128);
            for (int n = 0; n < 4; ++n) bfq[n] = *(u16x8*)ldsp(sB, wc * 64 + n * 16 + c, kb, 128);
            for (int m = 0; m < 4; ++m)
                for (int n = 0; n < 4; ++n)
                    acc[m][n] = mfma16(af[m], bfq[n], acc[m][n]);
        }
    }
    for (int m = 0; m < 4; ++m)
        for (int n = 0; n < 4; ++n) {
            int row0 = bm0 + wr * 64 + m * 16 + g * 4;
            int col  = bn0 + wc * 64 + n * 16 + c;
            for (int j = 0; j < 4; ++j)
                out[(size_t)(row0 + j) * DA + col] = acc[m][n][j];
        }
}

// ---------------------------------------------------------------------------
extern "C" void kernel_launch(void* const* d_in, const int* in_sizes, int n_in,
                              void* d_out, int out_size, void* d_ws, size_t ws_size,
                              hipStream_t stream) {
    const float* queries = (const float*)d_in[0];
    const float* keys    = (const float*)d_in[1];
    const float* values  = (const float*)d_in[2];
    const float* Eq      = (const float*)d_in[3];
    const float* Ek      = (const float*)d_in[4];
    const float* Ev      = (const float*)d_in[5];
    const float* Wout    = (const float*)d_in[6];
    float* out = (float*)d_out;

    const size_t PROJ = (size_t)NH * SEQ * DKV;   // 8,388,608 elems
    const size_t TSZ  = (size_t)DA * DA;          // 4,194,304 elems
    const size_t ASZ  = (size_t)SEQ * DA;         // 8,388,608 elems
    u16* p  = (u16*)d_ws;
    u16* QH = p; p += PROJ;
    u16* QL = p; p += PROJ;
    u16* KH = p; p += PROJ;
    u16* KL = p; p += PROJ;
    u16* VT = p; p += PROJ;
    u16* AB = p; p += (size_t)SEQ * NH * DKV;
    u16* TH = p; p += TSZ;
    u16* TL = p; p += TSZ;
    u16* Sh = p; p += ASZ;
    u16* Sl = p; p += ASZ;

    dim3 tgE(DA / 32, DKV / 32, NH);   // E transposes
    dim3 tgW(DA / 32, DA / 32, 1);     // W transpose
    dim3 pg(SEQ / 128, NH);
    const int NELEM = SEQ * DA;

    // Q chain (queries pre-scaled by 1/128 — power of 2, exact)
    transpose_split_k<<<tgE, 256, 0, stream>>>(Eq, TH, TL, DA, DKV);
    split_cvt_k<<<2048, 256, 0, stream>>>(queries, Sh, Sl, 1.0f / 128.0f, NELEM);
    proj2_k<2><<<pg, 256, 0, stream>>>(Sh, Sl, TH, TL, QH, QL);
    // K chain
    transpose_split_k<<<tgE, 256, 0, stream>>>(Ek, TH, TL, DA, DKV);
    split_cvt_k<<<2048, 256, 0, stream>>>(keys, Sh, Sl, 1.0f, NELEM);
    proj2_k<1><<<pg, 256, 0, stream>>>(Sh, Sl, TH, TL, KH, KL);
    // V chain (hi only)
    transpose_split_k<<<tgE, 256, 0, stream>>>(Ev, TH, nullptr, DA, DKV);
    split_cvt_k<<<2048, 256, 0, stream>>>(values, Sh, nullptr, 1.0f, NELEM);
    proj2_k<0><<<pg, 256, 0, stream>>>(Sh, nullptr, TH, nullptr, VT, nullptr);
    // W transpose (hi only)
    transpose_split_k<<<tgW, 256, 0, stream>>>(Wout, TH, nullptr, DA, DA);
    // attention (256 blocks, 512 thr)
    attn_k<<<dim3(SEQ / 256 * NH), 512, 0, stream>>>(QH, QL, KH, KL, VT, AB);
    // output projection
    gemm_out_k<<<dim3(SEQ / 128, DA / 128), 256, 0, stream>>>(AB, TH, out);
}

// Round 17
// 574.266 us; speedup vs baseline: 1.1391x; 1.0045x over previous
//
#include <hip/hip_runtime.h>

typedef unsigned short u16;
typedef __attribute__((ext_vector_type(4)))  float  f32x4;
typedef __attribute__((ext_vector_type(16))) float  f32x16;
typedef __attribute__((ext_vector_type(4)))  float  float4v;
typedef __attribute__((ext_vector_type(4)))  unsigned short u16x4;
typedef __attribute__((ext_vector_type(8)))  unsigned short u16x8;
typedef __attribute__((ext_vector_type(8)))  short s16x8;
typedef __attribute__((ext_vector_type(4)))  unsigned int u32x4;

#define SEQ 4096
#define DA  2048
#define NH  16
#define DKV 128

__device__ __forceinline__ u16 f2bf(float f) {
    unsigned u = __builtin_bit_cast(unsigned, f);
    u += 0x7FFFu + ((u >> 16) & 1u);           // round-nearest-even
    return (u16)(u >> 16);
}
__device__ __forceinline__ float bf2f(u16 h) {
    return __builtin_bit_cast(float, (unsigned)h << 16);
}
__device__ __forceinline__ f32x4 mfma16(u16x8 a, u16x8 b, f32x4 c) {
    return __builtin_amdgcn_mfma_f32_16x16x32_bf16(
        __builtin_bit_cast(s16x8, a), __builtin_bit_cast(s16x8, b), c, 0, 0, 0);
}
__device__ __forceinline__ f32x16 mfma32(u16x8 a, u16x8 b, f32x16 c) {
    return __builtin_amdgcn_mfma_f32_32x32x16_bf16(
        __builtin_bit_cast(s16x8, a), __builtin_bit_cast(s16x8, b), c, 0, 0, 0);
}
__device__ __forceinline__ unsigned cvtpk(float lo, float hi) {
    unsigned r;
    asm("v_cvt_pk_bf16_f32 %0, %1, %2" : "=v"(r) : "v"(lo), "v"(hi));
    return r;
}
// direct-to-LDS 16B load: per-lane global src, wave-uniform LDS base (+lane*16)
__device__ __forceinline__ void gld16(const u16* g, u16* l) {
    __builtin_amdgcn_global_load_lds(
        (const __attribute__((address_space(1))) unsigned int*)g,
        (__attribute__((address_space(3))) unsigned int*)l, 16, 0, 0);
}
// swizzled LDS addressing, 128B rows: XOR row&7 into byte-bit-4..6
__device__ __forceinline__ char* ldsp(void* base, int row, int bcol, int rowbytes) {
    int off = row * rowbytes + bcol;
    off ^= (row & 7) << 4;
    return (char*)base + off;
}
// swizzled LDS addressing, 256B rows: XOR row&15 into byte-bit-4..7
__device__ __forceinline__ char* ldsp256(void* base, int row, int bcol) {
    int off = row * 256 + bcol;
    off ^= (row & 15) << 4;
    return (char*)base + off;
}

// ---------------------------------------------------------------------------
// Transpose + split-convert: in f32 [B][R][C] -> oh/ol bf16 [B][C][R]
// ---------------------------------------------------------------------------
__global__ void transpose_split_k(const float* __restrict__ in, u16* __restrict__ oh,
                                  u16* __restrict__ ol, int R, int C) {
    __shared__ float tile[32][33];
    int b  = blockIdx.z;
    int r0 = blockIdx.x * 32, c0 = blockIdx.y * 32;
    const float* src = in + (size_t)b * R * C;
    int t = threadIdx.x;
    {
        int cl = t & 31, r = t >> 5;
        for (int i = 0; i < 4; ++i)
            tile[r + 8 * i][cl] = src[(size_t)(r0 + r + 8 * i) * C + (c0 + cl)];
    }
    __syncthreads();
    int rl = t & 31, c = t >> 5;
    size_t obase = (size_t)b * R * C;
    for (int i = 0; i < 4; ++i) {
        int cw = c + 8 * i;
        float x = tile[rl][cw];
        u16 h = f2bf(x);
        size_t o = obase + (size_t)(c0 + cw) * R + (r0 + rl);
        oh[o] = h;
        if (ol) ol[o] = f2bf(x - bf2f(h));
    }
}

// ---------------------------------------------------------------------------
// Row-major split-convert: in f32 [n], scale -> oh (hi), ol (lo residual)
// ---------------------------------------------------------------------------
__global__ void split_cvt_k(const float* __restrict__ in, u16* __restrict__ oh,
                            u16* __restrict__ ol, float scale, int n) {
    int stride = gridDim.x * 256 * 4;
    for (int i = (blockIdx.x * 256 + threadIdx.x) * 4; i < n; i += stride) {
        float4v v = *(const float4v*)(in + i);
        u16x4 hv, lv;
#pragma unroll
        for (int j = 0; j < 4; ++j) {
            float x = v[j] * scale;
            u16 hh = f2bf(x);
            hv[j] = hh;
            lv[j] = f2bf(x - bf2f(hh));
        }
        *(u16x4*)(oh + i) = hv;
        if (ol) *(u16x4*)(ol + i) = lv;
    }
}

// ---------------------------------------------------------------------------
// Projection GEMM v2 (R12-exact): pure-bf16 inputs, gld16 staging,
// single-buffered BK=64, 2 blocks/CU.
// MODE 0: V (1 chain) -> VT[h][v][s]. MODE 1: K split. MODE 2: Q split.
// ---------------------------------------------------------------------------
template <int MODE>
__global__ void __launch_bounds__(256, 2) proj2_k(const u16* __restrict__ ASh,
                                                  const u16* __restrict__ ASl,
                                                  const u16* __restrict__ BTh,
                                                  const u16* __restrict__ BTl,
                                                  u16* __restrict__ Oh,
                                                  u16* __restrict__ Ol) {
    __shared__ u16 sAh[128 * 64];
    __shared__ u16 sBh[128 * 64];
    __shared__ u16 sAl[MODE ? 128 * 64 : 8];
    __shared__ u16 sBl[MODE ? 128 * 64 : 8];

    int t = threadIdx.x;
    int h = blockIdx.y;
    int bm0 = blockIdx.x * 128;
    int lane = t & 63, w = t >> 6, wr = w >> 1, wc = w & 1;
    int g = lane >> 4, c = lane & 15;

    int rin = lane >> 3;
    int cg  = (lane & 7) ^ rin;

    f32x4 acc[4][4] = {};

    for (int k0 = 0; k0 < DA; k0 += 64) {
        __syncthreads();
#pragma unroll
        for (int j = 0; j < 4; ++j) {
            int chunk = w * 4 + j;
            int r = chunk * 8 + rin;
            size_t ga = (size_t)(bm0 + r) * DA + k0 + cg * 8;
            size_t gb = ((size_t)h * 128 + r) * DA + k0 + cg * 8;
            gld16(ASh + ga, &sAh[chunk * 512]);
            gld16(BTh + gb, &sBh[chunk * 512]);
            if (MODE) {
                gld16(ASl + ga, &sAl[chunk * 512]);
                gld16(BTl + gb, &sBl[chunk * 512]);
            }
        }
        __syncthreads();

        for (int kc = 0; kc < 2; ++kc) {
            int kb = (kc * 32 + g * 8) * 2;
            u16x8 ah[4], al[4], bh[4], bl[4];
            for (int m = 0; m < 4; ++m) {
                int row = wr * 64 + m * 16 + c;
                ah[m] = *(u16x8*)ldsp(sAh, row, kb, 128);
                if (MODE) al[m] = *(u16x8*)ldsp(sAl, row, kb, 128);
            }
            for (int n = 0; n < 4; ++n) {
                int row = wc * 64 + n * 16 + c;
                bh[n] = *(u16x8*)ldsp(sBh, row, kb, 128);
                if (MODE) bl[n] = *(u16x8*)ldsp(sBl, row, kb, 128);
            }
            for (int m = 0; m < 4; ++m)
                for (int n = 0; n < 4; ++n) {
                    acc[m][n] = mfma16(ah[m], bh[n], acc[m][n]);
                    if (MODE) {
                        acc[m][n] = mfma16(ah[m], bl[n], acc[m][n]);
                        acc[m][n] = mfma16(al[m], bh[n], acc[m][n]);
                    }
                }
        }
    }

    for (int m = 0; m < 4; ++m)
        for (int n = 0; n < 4; ++n) {
            int col  = wc * 64 + n * 16 + c;
            int row0 = bm0 + wr * 64 + m * 16 + g * 4;
            if (MODE == 0) {
                u16x4 pv;
                for (int j = 0; j < 4; ++j) pv[j] = f2bf(acc[m][n][j]);
                *(u16x4*)(Oh + ((size_t)h * DKV + col) * SEQ + row0) = pv;
            } else {
                for (int j = 0; j < 4; ++j) {
                    float v = acc[m][n][j];
                    u16 hh = f2bf(v);
                    size_t o = ((size_t)h * SEQ + row0 + j) * DKV + col;
                    Oh[o] = hh;
                    Ol[o] = f2bf(v - bf2f(hh));
                }
            }
        }
}

// ---------------------------------------------------------------------------
// Flash attention — R12-exact kernel (measured 263 µs, absmax 64).
// ---------------------------------------------------------------------------
__global__ void __launch_bounds__(512, 1) attn_k(const u16* __restrict__ QH,
                                                 const u16* __restrict__ QL,
                                                 const u16* __restrict__ KH,
                                                 const u16* __restrict__ KL,
                                                 const u16* __restrict__ VT,
                                                 u16* __restrict__ Abuf) {
    __shared__ u16 sKh[2][64 * 128];
    __shared__ u16 sKl[2][64 * 128];
    __shared__ u16 sV [2][64 * 128];   // [64 rows][256B]: row r, half p = vdim p*64+r

    int t = threadIdx.x, lane = t & 63, w = t >> 6;   // w in 0..7
    int bid = blockIdx.x;
    int h  = (bid & 7) + 8 * ((bid >> 3) & 1);        // XCD x serves heads {x, x+8}
    int q0 = (bid >> 4) * 256;
    int c = lane & 31, hi = lane >> 5;
    int qrow = q0 + w * 32 + c;

    // Q fragments (B-operand layout): lane holds Q[qrow][dc*16 + hi*8 .. +7]
    u16x8 qh[8], ql[8];
    {
        size_t base = ((size_t)h * SEQ + qrow) * DKV + hi * 8;
#pragma unroll
        for (int dc = 0; dc < 8; ++dc) {
            qh[dc] = *(const u16x8*)(QH + base + dc * 16);
            ql[dc] = *(const u16x8*)(QL + base + dc * 16);
        }
    }

    f32x16 o[4] = {};
    float mrun = -3e38f, lrun = 0.f;

    const size_t kroot = (size_t)h * SEQ * DKV;
    const size_t vroot = (size_t)h * DKV * SEQ;

    auto stage = [&](int kv, int b) {
        const u16* khp = KH + kroot + (size_t)kv * DKV;
        const u16* klp = KL + kroot + (size_t)kv * DKV;
        const u16* vtp = VT + vroot + kv;
#pragma unroll
        for (int j = 0; j < 2; ++j) {
            int ci = w * 2 + j;                      // 1KB chunk index (0..15)
            int rK = ci * 4 + (lane >> 4);           // LDS row 0..63
            int cK = (lane & 15) ^ (rK & 15);        // inverse-swizzled granule col
            gld16(khp + rK * DKV + cK * 8, &sKh[b][ci * 512]);
            gld16(klp + rK * DKV + cK * 8, &sKl[b][ci * 512]);
            int vd = ((cK >> 3) << 6) + rK;          // vdim for V gather
            gld16(vtp + (size_t)vd * SEQ + (cK & 7) * 8, &sV[b][ci * 512]);
        }
    };

    stage(0, 0);
    const int NT = SEQ / 64;
    for (int it = 0; it < NT; ++it) {
        int b = it & 1;
        __syncthreads();               // drains own stage(it) loads, syncs all waves
        if (it + 1 < NT) stage((it + 1) * 64, b ^ 1);   // in flight under compute

        // S^T = K * Q^T : s[kt] holds S[kv=(r&3)+8*(r>>2)+4*hi + 32*kt][q=c]
        f32x16 s[2] = {};
        __builtin_amdgcn_s_setprio(1);
#pragma unroll
        for (int kt = 0; kt < 2; ++kt) {
#pragma unroll
            for (int dc = 0; dc < 8; ++dc) {
                u16x8 kh = *(u16x8*)ldsp256(sKh[b], kt * 32 + c, dc * 32 + hi * 16);
                u16x8 kl = *(u16x8*)ldsp256(sKl[b], kt * 32 + c, dc * 32 + hi * 16);
                s[kt] = mfma32(kh, qh[dc], s[kt]);
                s[kt] = mfma32(kl, qh[dc], s[kt]);
                s[kt] = mfma32(kh, ql[dc], s[kt]);
            }
        }
        __builtin_amdgcn_s_setprio(0);

        // online softmax with T13 defer-rescale (THR=8)
        float vmax = s[0][0];
#pragma unroll
        for (int r = 1; r < 16; ++r) vmax = fmaxf(vmax, s[0][r]);
#pragma unroll
        for (int r = 0; r < 16; ++r) vmax = fmaxf(vmax, s[1][r]);
        vmax = fmaxf(vmax, __shfl_xor(vmax, 32));
        if (!__all(vmax <= mrun + 8.0f)) {
            float mnew = fmaxf(mrun, vmax);
            float corr = __expf(mrun - mnew);
            mrun = mnew;
            lrun *= corr;
#pragma unroll
            for (int vt = 0; vt < 4; ++vt)
#pragma unroll
                for (int r = 0; r < 16; ++r) o[vt][r] *= corr;
        }
        float rs = 0.f;
#pragma unroll
        for (int kt = 0; kt < 2; ++kt)
#pragma unroll
            for (int r = 0; r < 16; ++r) {
                float p = __expf(s[kt][r] - mrun);
                s[kt][r] = p;
                rs += p;
            }
        rs += __shfl_xor(rs, 32);
        lrun += rs;

        // P -> B-frag (in-register) and PV: O^T += V^T · P^T
#pragma unroll
        for (int kt = 0; kt < 2; ++kt) {
            unsigned wv[8], xw[8];
#pragma unroll
            for (int i = 0; i < 8; ++i) wv[i] = cvtpk(s[kt][2 * i], s[kt][2 * i + 1]);
#pragma unroll
            for (int i = 0; i < 8; ++i) xw[i] = (unsigned)__shfl_xor((int)wv[i], 32);
            __builtin_amdgcn_s_setprio(1);
#pragma unroll
            for (int kc = 0; kc < 2; ++kc) {
                u32x4 pw;
                pw[0] = hi ? xw[4 * kc + 2] : wv[4 * kc + 0];
                pw[1] = hi ? xw[4 * kc + 3] : wv[4 * kc + 1];
                pw[2] = hi ? wv[4 * kc + 2] : xw[4 * kc + 0];
                pw[3] = hi ? wv[4 * kc + 3] : xw[4 * kc + 1];
                u16x8 pf = __builtin_bit_cast(u16x8, pw);
#pragma unroll
                for (int vt = 0; vt < 4; ++vt) {
                    int v = vt * 32 + c;
                    u16x8 vf = *(u16x8*)ldsp256(sV[b], v & 63,
                                                ((v >> 6) << 7) + kt * 64 + kc * 32 + hi * 16);
                    o[vt] = mfma32(vf, pf, o[vt]);
                }
            }
            __builtin_amdgcn_s_setprio(0);
        }
    }

    float inv = 1.0f / lrun;
#pragma unroll
    for (int vt = 0; vt < 4; ++vt)
#pragma unroll
        for (int rg = 0; rg < 4; ++rg) {
            u16x4 pv;
#pragma unroll
            for (int j = 0; j < 4; ++j) pv[j] = f2bf(o[vt][rg * 4 + j] * inv);
            *(u16x4*)(Abuf + (size_t)qrow * (NH * DKV) + h * DKV + vt * 32 + rg * 8 + hi * 4) = pv;
        }
}

// ---------------------------------------------------------------------------
// Final GEMM v2 (R12-exact): gld16 staging, single-buffered BK=64.
// ---------------------------------------------------------------------------
__global__ void __launch_bounds__(256, 2) gemm_out_k(const u16* __restrict__ Abuf,
                                                     const u16* __restrict__ WT,
                                                     float* __restrict__ out) {
    __shared__ u16 sA[128 * 64];
    __shared__ u16 sB[128 * 64];
    int t = threadIdx.x, lane = t & 63, w = t >> 6, wr = w >> 1, wc = w & 1;
    int g = lane >> 4, c = lane & 15;
    int bm0 = blockIdx.x * 128, bn0 = blockIdx.y * 128;
    int rin = lane >> 3;
    int cg  = (lane & 7) ^ rin;
    f32x4 acc[4][4] = {};

    for (int k0 = 0; k0 < DA; k0 += 64) {
        __syncthreads();
#pragma unroll
        for (int j = 0; j < 4; ++j) {
            int chunk = w * 4 + j;
            int r = chunk * 8 + rin;
            gld16(Abuf + (size_t)(bm0 + r) * DA + k0 + cg * 8, &sA[chunk * 512]);
            gld16(WT   + (size_t)(bn0 + r) * DA + k0 + cg * 8, &sB[chunk * 512]);
        }
        __syncthreads();

        for (int kc = 0; kc < 2; ++kc) {
            int kb = (kc * 32 + g * 8) * 2;
            u16x8 af[4], bfq[4];
            for (int m = 0; m < 4; ++m) af[m]  = *(u16x8*)ldsp(sA, wr * 64 + m * 16 + c, kb, 128);
            for (int n = 0; n < 4; ++n) bfq[n] = *(u16x8*)ldsp(sB, wc * 64 + n * 16 + c, kb, 128);
            for (int m = 0; m < 4; ++m)
                for (int n = 0; n < 4; ++n)
                    acc[m][n] = mfma16(af[m], bfq[n], acc[m][n]);
        }
    }
    for (int m = 0; m < 4; ++m)
        for (int n = 0; n < 4; ++n) {
            int row0 = bm0 + wr * 64 + m * 16 + g * 4;
            int col  = bn0 + wc * 64 + n * 16 + c;
            for (int j = 0; j < 4; ++j)
                out[(size_t)(row0 + j) * DA + col] = acc[m][n][j];
        }
}

// ---------------------------------------------------------------------------
extern "C" void kernel_launch(void* const* d_in, const int* in_sizes, int n_in,
                              void* d_out, int out_size, void* d_ws, size_t ws_size,
                              hipStream_t stream) {
    const float* queries = (const float*)d_in[0];
    const float* keys    = (const float*)d_in[1];
    const float* values  = (const float*)d_in[2];
    const float* Eq      = (const float*)d_in[3];
    const float* Ek      = (const float*)d_in[4];
    const float* Ev      = (const float*)d_in[5];
    const float* Wout    = (const float*)d_in[6];
    float* out = (float*)d_out;

    const size_t PROJ = (size_t)NH * SEQ * DKV;   // 8,388,608 elems
    const size_t TSZ  = (size_t)DA * DA;          // 4,194,304 elems
    const size_t ASZ  = (size_t)SEQ * DA;         // 8,388,608 elems
    u16* p  = (u16*)d_ws;
    u16* QH = p; p += PROJ;
    u16* QL = p; p += PROJ;
    u16* KH = p; p += PROJ;
    u16* KL = p; p += PROJ;
    u16* VT = p; p += PROJ;
    u16* AB = p; p += (size_t)SEQ * NH * DKV;
    u16* TH = p; p += TSZ;
    u16* TL = p; p += TSZ;
    u16* Sh = p; p += ASZ;
    u16* Sl = p; p += ASZ;

    dim3 tgE(DA / 32, DKV / 32, NH);   // E transposes
    dim3 tgW(DA / 32, DA / 32, 1);     // W transpose
    dim3 pg(SEQ / 128, NH);
    const int NELEM = SEQ * DA;

    // Q chain (queries pre-scaled by 1/128 — power of 2, exact)
    transpose_split_k<<<tgE, 256, 0, stream>>>(Eq, TH, TL, DA, DKV);
    split_cvt_k<<<2048, 256, 0, stream>>>(queries, Sh, Sl, 1.0f / 128.0f, NELEM);
    proj2_k<2><<<pg, 256, 0, stream>>>(Sh, Sl, TH, TL, QH, QL);
    // K chain
    transpose_split_k<<<tgE, 256, 0, stream>>>(Ek, TH, TL, DA, DKV);
    split_cvt_k<<<2048, 256, 0, stream>>>(keys, Sh, Sl, 1.0f, NELEM);
    proj2_k<1><<<pg, 256, 0, stream>>>(Sh, Sl, TH, TL, KH, KL);
    // V chain (hi only)
    transpose_split_k<<<tgE, 256, 0, stream>>>(Ev, TH, nullptr, DA, DKV);
    split_cvt_k<<<2048, 256, 0, stream>>>(values, Sh, nullptr, 1.0f, NELEM);
    proj2_k<0><<<pg, 256, 0, stream>>>(Sh, nullptr, TH, nullptr, VT, nullptr);
    // W transpose (hi only)
    transpose_split_k<<<tgW, 256, 0, stream>>>(Wout, TH, nullptr, DA, DA);
    // attention (256 blocks, 512 thr)
    attn_k<<<dim3(SEQ / 256 * NH), 512, 0, stream>>>(QH, QL, KH, KL, VT, AB);
    // output projection
    gemm_out_k<<<dim3(SEQ / 128, DA / 128), 256, 0, stream>>>(AB, TH, out);
}